// Round 18
// baseline (72.428 us; speedup 1.0000x reference)
//
#include <hip/hip_runtime.h>

#define N 8192
#define EPS 1e-5f
#define LOG2E 1.4426950408889634f
#define LN2d  0.6931471805599453

#define TR 64          // rows per tile
#define TC 256         // cols per tile
#define NBJ 32         // N/TC col-tiles
#define NBI 128        // N/TR row-tiles
#define RPW 16         // rows per wave (4 waves/block)
#define CAPW 512       // per-wave LDS edge buffer entries
#define SEG_W 4096     // worst-case edges per wave segment (RPW*TC)
#define NTILES 2112    // active upper-tri tiles
#define NSEG (NTILES * 4)
#define RMAX 512       // max degree range for histogram algebra path
#define NA 32          // A-term chunk blocks (8192/256)
#define NDR 1024       // dense fallback blocks (R>RMAX only; 4 row-pairs each)
#define EDGE0 (NA + 1 + NDR)
#define NFB 1024       // tiny-ws fallback blocks

// ws layout (bytes):
//   accv [0,4096)   64 double slots, stride 8 doubles
//   deg  [4096, +32768)          -- memset with accv (36864 B)
//   cnt  [36864, +NSEG*4)
//   edges[..., +NSEG*SEG_W*4)    total ~138 MB
static const size_t OFF_ACC = 0;
static const size_t OFF_DEG = 4096;
static const size_t OFF_CNT = OFF_DEG + (size_t)N * 4;
static const size_t OFF_EDG = OFF_CNT + (size_t)NSEG * 4;
static const size_t WS_NEED = OFF_EDG + (size_t)NSEG * SEG_W * 4;

__device__ __forceinline__ unsigned mbcnt64(unsigned long long m) {
    return __builtin_amdgcn_mbcnt_hi((unsigned)(m >> 32),
           __builtin_amdgcn_mbcnt_lo((unsigned)m, 0u));
}

// Pass 1 (round-12 champion body, unchanged): stream the upper triangle once.
__global__ __launch_bounds__(256) void k_pass1(const float* __restrict__ g,
        float* __restrict__ deg, unsigned* __restrict__ cnt,
        unsigned* __restrict__ edges, const int segmode) {
    const int bj = (int)blockIdx.x & (NBJ - 1);
    const int bi = (int)blockIdx.x >> 5;
    if (bi > 4 * bj + 3) return;                 // tile fully below diagonal
    const int r0 = bi * TR, c0 = bj * TC;
    const int wave = threadIdx.x >> 6, lane = threadIdx.x & 63;
    const int aid = 2 * bj * (bj + 1) + bi;      // compact active-tile index

    __shared__ float    scol[TC];
    __shared__ unsigned buf[4][CAPW];
    scol[threadIdx.x] = 0.f;
    __syncthreads();

    const int c = c0 + lane * 4;
    const int rbase = r0 + wave * RPW;
    const float* __restrict__ gp = g + (size_t)rbase * N + c;
    unsigned* __restrict__ myseg = edges + ((size_t)aid * 4 + wave) * SEG_W;
    unsigned wc = 0, wflushed = 0;               // wave-uniform registers
    float ca0 = 0.f, ca1 = 0.f, ca2 = 0.f, ca3 = 0.f;

#define EMIT(BB, PRED, OFFv) \
    if (BB) { if (segmode && (PRED)) buf[wave][wc + mbcnt64(BB)] = etag | (OFFv); \
        const unsigned p_ = __popcll(BB); wc += p_; rsum += p_; }

#define FLUSHCHK \
    if (segmode && wc > (unsigned)(CAPW - 256)) { \
        for (unsigned t_ = lane; t_ < wc; t_ += 64) myseg[wflushed + t_] = buf[wave][t_]; \
        wflushed += wc; wc = 0; }

    if (r0 + TR <= c0) {
        #pragma unroll 4
        for (int k = 0; k < RPW; ++k) {
            const float4 v = *reinterpret_cast<const float4*>(gp + (size_t)k * N);
            FLUSHCHK
            ca0 += v.x; ca1 += v.y; ca2 += v.z; ca3 += v.w;
            const unsigned long long b0 = __ballot(v.x != 0.f);
            const unsigned long long b1 = __ballot(v.y != 0.f);
            const unsigned long long b2 = __ballot(v.z != 0.f);
            const unsigned long long b3 = __ballot(v.w != 0.f);
            if (b0 | b1 | b2 | b3) {
                const int gr = rbase + k;
                const unsigned etag = ((unsigned)gr << 16) | (unsigned)c;
                unsigned rsum = 0;
                EMIT(b0, v.x != 0.f, 0u)
                EMIT(b1, v.y != 0.f, 1u)
                EMIT(b2, v.z != 0.f, 2u)
                EMIT(b3, v.w != 0.f, 3u)
                if (lane == 0) atomicAdd(&deg[gr], (float)rsum);
            }
        }
    } else {
        for (int k = 0; k < RPW; ++k) {
            const int gr = rbase + k;
            const float4 v = *reinterpret_cast<const float4*>(gp + (size_t)k * N);
            FLUSHCHK
            const bool a0 = (v.x != 0.f) && (c + 0 >= gr);
            const bool a1 = (v.y != 0.f) && (c + 1 >= gr);
            const bool a2 = (v.z != 0.f) && (c + 2 >= gr);
            const bool a3 = (v.w != 0.f) && (c + 3 >= gr);
            ca0 += (c + 0 > gr) ? v.x : 0.f;
            ca1 += (c + 1 > gr) ? v.y : 0.f;
            ca2 += (c + 2 > gr) ? v.z : 0.f;
            ca3 += (c + 3 > gr) ? v.w : 0.f;
            const unsigned long long b0 = __ballot(a0);
            const unsigned long long b1 = __ballot(a1);
            const unsigned long long b2 = __ballot(a2);
            const unsigned long long b3 = __ballot(a3);
            if (b0 | b1 | b2 | b3) {
                const unsigned etag = ((unsigned)gr << 16) | (unsigned)c;
                unsigned rsum = 0;
                EMIT(b0, a0, 0u)
                EMIT(b1, a1, 1u)
                EMIT(b2, a2, 2u)
                EMIT(b3, a3, 3u)
                if (lane == 0) atomicAdd(&deg[gr], (float)rsum);
            }
        }
    }
#undef EMIT
#undef FLUSHCHK

    if (segmode) {
        for (unsigned t = lane; t < wc; t += 64) myseg[wflushed + t] = buf[wave][t];
        if (lane == 0) cnt[aid * 4 + wave] = wflushed + wc;
    }
    if (ca0 != 0.f) atomicAdd(&scol[lane * 4 + 0], ca0);
    if (ca1 != 0.f) atomicAdd(&scol[lane * 4 + 1], ca1);
    if (ca2 != 0.f) atomicAdd(&scol[lane * 4 + 2], ca2);
    if (ca3 != 0.f) atomicAdd(&scol[lane * 4 + 3], ca3);
    __syncthreads();
    const float sv = scol[threadIdx.x];
    if (sv != 0.f) atomicAdd(&deg[c0 + threadIdx.x], sv);
}

// k_ll: dense S0 via histogram symmetrization + edge corrections + fallbacks.
//   f(x,y) = ln2 * log2(1.00001 - rcp(1 + exp2(a2*x + b2*y + s2)))
//   S0 = 0.5*(T_full + A + D_diag):
//     T_full = sum_{a,b} h[a]h[b] f(a,b); D_diag = sum_a h[a] f(a,a)   [1 blk]
//     A = sum_{i<j} [f(di,dj)-f(dj,di)]   [32 chunk blocks: prefix-hist cross
//                                          pairs + direct within-chunk pairs]
__global__ __launch_bounds__(256) void k_ll(const float* __restrict__ g,
        const float* __restrict__ deg, const float* __restrict__ params,
        const unsigned* __restrict__ cnt, const unsigned* __restrict__ edges,
        double* __restrict__ accv, const int segmode) {
    __shared__ double wsum[4];
    __shared__ float  srange[8];
    __shared__ int    hist[RMAX];
    __shared__ float  dchunk[256];
    const int tid = threadIdx.x;
    const int wv = tid >> 6, ln = tid & 63;
    const int b = blockIdx.x;
    const float alpha = params[0], beta = params[1], sigma = params[2];
    const float a2 = alpha * LOG2E, b2 = beta * LOG2E, s2 = sigma * LOG2E;
    double dlocal = 0.0;

#define F2(X, Y) __builtin_amdgcn_logf(1.00001f - __builtin_amdgcn_rcpf(1.f + \
        __builtin_amdgcn_exp2f(fmaf(a2, (X), fmaf(b2, (Y), s2)))))

    if (b < EDGE0) {
        if (segmode) {
            // deterministic global degree range (identical in every block)
            float mn = 3.0e38f, mx = -3.0e38f;
            for (int j = tid; j < N; j += 256) {
                const float d = deg[j];
                mn = fminf(mn, d); mx = fmaxf(mx, d);
            }
            #pragma unroll
            for (int off = 32; off; off >>= 1) {
                mn = fminf(mn, __shfl_xor(mn, off));
                mx = fmaxf(mx, __shfl_xor(mx, off));
            }
            if (ln == 0) { srange[wv] = mn; srange[4 + wv] = mx; }
            __syncthreads();
            mn = fminf(fminf(srange[0], srange[1]), fminf(srange[2], srange[3]));
            mx = fmaxf(fmaxf(srange[4], srange[5]), fmaxf(srange[6], srange[7]));
            const int dmin = (int)mn;
            const int R = (int)mx - dmin + 1;

            if (b < NA) {
                if (R <= RMAX) {                 // A-term chunk block
                    const int j0 = b * 256;
                    for (int i = tid; i < R; i += 256) hist[i] = 0;
                    __syncthreads();
                    for (int i = tid; i < j0; i += 256)
                        atomicAdd(&hist[(int)deg[i] - dmin], 1);
                    dchunk[tid] = deg[j0 + tid];
                    __syncthreads();
                    const float dj = dchunk[tid];
                    double accA = 0.0;
                    for (int i = 0; i < tid; ++i) {     // within-chunk i<j
                        const float di = dchunk[i];
                        accA += (double)(F2(di, dj) - F2(dj, di));
                    }
                    for (int d = 0; d < R; ++d) {       // cross: i < j0 <= j
                        const int c = hist[d];
                        if (c) {
                            const float dd = (float)(dmin + d);
                            accA += (double)c * (double)(F2(dd, dj) - F2(dj, dd));
                        }
                    }
                    dlocal = accA * 0.5 * LN2d;
                }
            } else if (b == NA) {
                if (R <= RMAX) {                 // T_full + D_diag block
                    for (int i = tid; i < R; i += 256) hist[i] = 0;
                    __syncthreads();
                    for (int i = tid; i < N; i += 256)
                        atomicAdd(&hist[(int)deg[i] - dmin], 1);
                    __syncthreads();
                    double accT = 0.0;
                    const int RR = R * R;
                    for (int cell = tid; cell < RR; cell += 256) {
                        const int a = cell / R, bb = cell - a * R;
                        const long long c = (long long)hist[a] * hist[bb];
                        if (c) accT += (double)c *
                            (double)F2((float)(dmin + a), (float)(dmin + bb));
                    }
                    for (int a = tid; a < R; a += 256) {  // diagonal
                        if (hist[a]) accT += (double)hist[a] *
                            (double)F2((float)(dmin + a), (float)(dmin + a));
                    }
                    dlocal = accT * 0.5 * LN2d;
                }
            } else {
                if (R > RMAX) {                  // adversarial spread: direct
                    const int db = b - NA - 1;   // 0..NDR-1, 4 row-pairs each
                    float ls = 0.f;
                    for (int q = 0; q < 4; ++q) {
                        const int r1 = db + q * NDR, r2 = N - 1 - r1;
                        const float dr1 = deg[r1], dr2 = deg[r2];
                        for (int j = r1 + tid; j < N; j += 256) ls += F2(dr1, deg[j]);
                        for (int j = r2 + tid; j < N; j += 256) ls += F2(dr2, deg[j]);
                    }
                    dlocal = (double)ls * LN2d;
                }
            }
        }
    } else if (b < EDGE0 + NTILES) {
        if (!segmode) return;
        const int aid = b - EDGE0;
        float local = 0.f;
        for (int w = 0; w < 4; ++w) {
            const unsigned n = cnt[aid * 4 + w];
            const unsigned* __restrict__ seg = edges + ((size_t)aid * 4 + w) * SEG_W;
            for (unsigned t = tid; t < n; t += 256) {
                const unsigned e = seg[t];
                const float di = deg[e >> 16];
                const float dj = deg[e & 0xffffu];
                const float s = fmaf(alpha, di, fmaf(beta, dj, sigma));
                const float p = __fdividef(1.f, 1.f + __expf(s));
                local += __logf(p + EPS) - __logf(1.f - p + EPS);
            }
        }
        dlocal = (double)local;
    } else {
        if (segmode) return;                     // tiny-ws graph-scan fallback
        const int rb = b - EDGE0 - NTILES;
        for (int q = 0; q < 8; ++q) {
            const int i = rb * 8 + q;
            const float base = fmaf(alpha, deg[i], sigma);
            float rl = 0.f;
            for (int j = i + tid; j < N; j += 256) {
                const float s = fmaf(beta, deg[j], base);
                const float p = __fdividef(1.f, 1.f + __expf(s));
                const float gv = g[(size_t)i * N + j];
                rl += (gv != 0.f) ? __logf(p + EPS) : __logf(1.f - p + EPS);
            }
            dlocal += (double)rl;
        }
    }
#undef F2

    #pragma unroll
    for (int off = 32; off; off >>= 1) dlocal += __shfl_xor(dlocal, off);
    if (ln == 0) wsum[wv] = dlocal;
    __syncthreads();
    if (tid == 0) {
        const double t = (wsum[0] + wsum[1]) + (wsum[2] + wsum[3]);
        if (t != 0.0) atomicAdd(&accv[(b & 63) * 8], t);   // 64 spread slots
    }
}

__global__ void k_final(const double* __restrict__ accv, float* __restrict__ out) {
    double v = accv[threadIdx.x * 8];
    #pragma unroll
    for (int off = 32; off; off >>= 1) v += __shfl_xor(v, off);
    if (threadIdx.x == 0) out[0] = (float)(-v);
}

extern "C" void kernel_launch(void* const* d_in, const int* in_sizes, int n_in,
                              void* d_out, int out_size, void* d_ws, size_t ws_size,
                              hipStream_t stream) {
    const float* params = (const float*)d_in[0];   // [alpha, beta, sigma]
    const float* graph  = (const float*)d_in[1];   // [N, N] fp32 0/1
    float* out = (float*)d_out;

    char* ws = (char*)d_ws;
    double*   accv  = (double*)(ws + OFF_ACC);
    float*    deg   = (float*)(ws + OFF_DEG);
    unsigned* cnt   = (unsigned*)(ws + OFF_CNT);
    unsigned* edges = (unsigned*)(ws + OFF_EDG);
    const int segmode = (ws_size >= WS_NEED) ? 1 : 0;

    hipMemsetAsync(ws, 0, OFF_DEG + (size_t)N * 4, stream);  // accv + deg
    k_pass1<<<NBI * NBJ, 256, 0, stream>>>(graph, deg, cnt, edges, segmode);
    const int llgrid = segmode ? (EDGE0 + NTILES) : (EDGE0 + NTILES + NFB);
    k_ll<<<llgrid, 256, 0, stream>>>(graph, deg, params, cnt, edges, accv, segmode);
    k_final<<<1, 64, 0, stream>>>(accv, out);
}